// Round 1
// baseline (1277.535 us; speedup 1.0000x reference)
//
#include <hip/hip_runtime.h>
#include <hip/hip_bf16.h>

#define NH 16
#define HD 64
#define EMB 1024
#define BB 4
#define TT 2048
#define MTOT (BB*TT)        // 8192 rows
#define N1 (3*NH*HD)        // 3072
#define KD EMB              // 1024

typedef __bf16 bf16x8 __attribute__((ext_vector_type(8)));
typedef float  f32x4  __attribute__((ext_vector_type(4)));
typedef __hip_bfloat16 hbf;

// ---------------- conversion kernels ----------------

__global__ void f32_to_bf16(const float* __restrict__ in, hbf* __restrict__ out, int n) {
    int i = blockIdx.x * blockDim.x + threadIdx.x;
    if (i < n) out[i] = __float2bfloat16(in[i]);
}

// out[c*R + r] = in[r*C + c]  (transpose while converting)
__global__ void f32_to_bf16_T(const float* __restrict__ in, hbf* __restrict__ out, int R, int C) {
    int i = blockIdx.x * blockDim.x + threadIdx.x;
    if (i < R * C) {
        int r = i / C, c = i % C;
        out[(size_t)c * R + r] = __float2bfloat16(in[i]);
    }
}

// ---------------- GEMM 1: qkv = x @ W_attn, scatter to per-head q/k/v ----------------
// A [MTOT,KD] bf16 row-major, Bt [N1,KD] bf16 (W_attn transposed).
// Wave-per-16x16-tile; A-frag a[j]=A[m0+c][k0+g*8+j], B-frag b[j]=Bt[n0+c][k0+g*8+j].
// D: row=g*4+r, col=c  (verified m89/m91 mapping).

__global__ __launch_bounds__(256) void gemm_qkv(
    const hbf* __restrict__ A, const hbf* __restrict__ Bt,
    hbf* __restrict__ qh, hbf* __restrict__ kh, hbf* __restrict__ vh)
{
    int wave = blockIdx.x * 4 + (threadIdx.x >> 6);
    int lane = threadIdx.x & 63;
    int g = lane >> 4, c = lane & 15;
    int nt = wave % (N1 / 16);
    int mt = wave / (N1 / 16);
    int m0 = mt * 16, n0 = nt * 16;

    const hbf* ap = A  + (size_t)(m0 + c) * KD + g * 8;
    const hbf* bp = Bt + (size_t)(n0 + c) * KD + g * 8;
    f32x4 acc = {0.f, 0.f, 0.f, 0.f};
    for (int k0 = 0; k0 < KD; k0 += 32) {
        bf16x8 a = *(const bf16x8*)(ap + k0);
        bf16x8 b = *(const bf16x8*)(bp + k0);
        acc = __builtin_amdgcn_mfma_f32_16x16x32_bf16(a, b, acc, 0, 0, 0);
    }
    // epilogue: decode col -> (which, h, d); wave-uniform since 16 | 64 | 1024
    int col   = n0 + c;
    int which = col / (NH * HD);
    int rem   = col % (NH * HD);
    int h = rem / HD, d = rem % HD;
    hbf* dst   = (which == 0) ? qh : (which == 1 ? kh : vh);
    float scale = (which == 0) ? 0.125f : 1.0f;   // 1/sqrt(HD), exact in bf16
    for (int r = 0; r < 4; ++r) {
        int row = m0 + g * 4 + r;
        int bb = row / TT, t = row % TT;
        size_t off = (((size_t)bb * NH + h) * TT + t) * HD + d;
        dst[off] = __float2bfloat16(acc[r] * scale);
    }
}

// ---------------- flash attention: one wave per (b, h, 16-row q tile) ----------------

__global__ __launch_bounds__(64) void attn(
    const hbf* __restrict__ qh, const hbf* __restrict__ kh, const hbf* __restrict__ vh,
    hbf* __restrict__ y)   // [MTOT, EMB], col = h*HD + d
{
    __shared__ __align__(16) hbf P[16][32];
    int qt = blockIdx.x % (TT / 16);
    int h  = (blockIdx.x / (TT / 16)) % NH;
    int b  = blockIdx.x / ((TT / 16) * NH);
    int lane = threadIdx.x;
    int g = lane >> 4, c = lane & 15;
    int t0 = qt * 16;

    const hbf* Q = qh + ((size_t)b * NH + h) * TT * HD;
    const hbf* K = kh + ((size_t)b * NH + h) * TT * HD;
    const hbf* V = vh + ((size_t)b * NH + h) * TT * HD;

    bf16x8 aq0 = *(const bf16x8*)(Q + (size_t)(t0 + c) * HD + g * 8);
    bf16x8 aq1 = *(const bf16x8*)(Q + (size_t)(t0 + c) * HD + 32 + g * 8);

    float m_s[4], l_s[4];
    f32x4 o[4];
    for (int r = 0; r < 4; ++r) { m_s[r] = -1e30f; l_s[r] = 0.f; }
    for (int n = 0; n < 4; ++n) o[n] = (f32x4){0.f, 0.f, 0.f, 0.f};

    int kend = t0 + 16;   // causal: keys 0..t0+15
    for (int k0 = 0; k0 < kend; k0 += 32) {
        // S tiles: keys [k0,k0+16) and [k0+16,k0+32)
        bf16x8 b00 = *(const bf16x8*)(K + (size_t)(k0 + c) * HD + g * 8);
        bf16x8 b01 = *(const bf16x8*)(K + (size_t)(k0 + c) * HD + 32 + g * 8);
        bf16x8 b10 = *(const bf16x8*)(K + (size_t)(k0 + 16 + c) * HD + g * 8);
        bf16x8 b11 = *(const bf16x8*)(K + (size_t)(k0 + 16 + c) * HD + 32 + g * 8);
        f32x4 s0 = {0.f, 0.f, 0.f, 0.f}, s1 = {0.f, 0.f, 0.f, 0.f};
        s0 = __builtin_amdgcn_mfma_f32_16x16x32_bf16(aq0, b00, s0, 0, 0, 0);
        s0 = __builtin_amdgcn_mfma_f32_16x16x32_bf16(aq1, b01, s0, 0, 0, 0);
        s1 = __builtin_amdgcn_mfma_f32_16x16x32_bf16(aq0, b10, s1, 0, 0, 0);
        s1 = __builtin_amdgcn_mfma_f32_16x16x32_bf16(aq1, b11, s1, 0, 0, 0);

        float p0[4], p1[4], alpha[4];
        for (int r = 0; r < 4; ++r) {
            int row = t0 + g * 4 + r;
            float v0 = (k0 + c      <= row) ? s0[r] : -1e30f;
            float v1 = (k0 + 16 + c <= row) ? s1[r] : -1e30f;
            float mx = fmaxf(v0, v1);
            for (int off = 1; off < 16; off <<= 1) mx = fmaxf(mx, __shfl_xor(mx, off));
            float mn = fmaxf(m_s[r], mx);
            float al = __expf(m_s[r] - mn);
            float e0 = __expf(v0 - mn);
            float e1 = __expf(v1 - mn);
            float sum = e0 + e1;
            for (int off = 1; off < 16; off <<= 1) sum += __shfl_xor(sum, off);
            l_s[r] = l_s[r] * al + sum;
            m_s[r] = mn;
            alpha[r] = al;
            p0[r] = e0; p1[r] = e1;
        }
        for (int n = 0; n < 4; ++n)
            for (int r = 0; r < 4; ++r) o[n][r] *= alpha[r];

        // P (D-layout) -> LDS -> A-operand layout
        __syncthreads();
        for (int r = 0; r < 4; ++r) {
            P[g * 4 + r][c]      = __float2bfloat16(p0[r]);
            P[g * 4 + r][16 + c] = __float2bfloat16(p1[r]);
        }
        __syncthreads();
        bf16x8 apf = *(const bf16x8*)(&P[c][g * 8]);

        // O += P @ V ; V B-frag b[j] = V[k0+g*8+j][n*16+c]
        for (int n = 0; n < 4; ++n) {
            bf16x8 bv;
            for (int j = 0; j < 8; ++j)
                bv[j] = *(const __bf16*)(V + (size_t)(k0 + g * 8 + j) * HD + n * 16 + c);
            o[n] = __builtin_amdgcn_mfma_f32_16x16x32_bf16(apf, bv, o[n], 0, 0, 0);
        }
    }

    for (int n = 0; n < 4; ++n) {
        for (int r = 0; r < 4; ++r) {
            int row = t0 + g * 4 + r;
            float val = o[n][r] / l_s[r];
            size_t off = ((size_t)(b * TT + row)) * EMB + h * HD + n * 16 + c;
            y[off] = __float2bfloat16(val);
        }
    }
}

// ---------------- GEMM 2: out = y @ W_proj + b_proj ----------------

__global__ __launch_bounds__(256) void gemm_out(
    const hbf* __restrict__ A, const hbf* __restrict__ Bt,
    const float* __restrict__ bias, float* __restrict__ out)
{
    int wave = blockIdx.x * 4 + (threadIdx.x >> 6);
    int lane = threadIdx.x & 63;
    int g = lane >> 4, c = lane & 15;
    int nt = wave % (EMB / 16);
    int mt = wave / (EMB / 16);
    int m0 = mt * 16, n0 = nt * 16;

    const hbf* ap = A  + (size_t)(m0 + c) * EMB + g * 8;
    const hbf* bp = Bt + (size_t)(n0 + c) * EMB + g * 8;
    f32x4 acc = {0.f, 0.f, 0.f, 0.f};
    for (int k0 = 0; k0 < EMB; k0 += 32) {
        bf16x8 a = *(const bf16x8*)(ap + k0);
        bf16x8 b = *(const bf16x8*)(bp + k0);
        acc = __builtin_amdgcn_mfma_f32_16x16x32_bf16(a, b, acc, 0, 0, 0);
    }
    float bv = bias[n0 + c];
    for (int r = 0; r < 4; ++r) {
        int row = m0 + g * 4 + r;
        out[(size_t)row * EMB + n0 + c] = acc[r] + bv;
    }
}

// ---------------- launch ----------------

extern "C" void kernel_launch(void* const* d_in, const int* in_sizes, int n_in,
                              void* d_out, int out_size, void* d_ws, size_t ws_size,
                              hipStream_t stream)
{
    const float* x      = (const float*)d_in[0];
    const float* W_attn = (const float*)d_in[1];
    const float* W_proj = (const float*)d_in[2];
    const float* b_proj = (const float*)d_in[3];
    float* out = (float*)d_out;

    char* ws = (char*)d_ws;
    hbf* xb    = (hbf*)ws; ws += (size_t)MTOT * KD * 2;     // 16.78 MB
    hbf* wab_t = (hbf*)ws; ws += (size_t)N1 * KD * 2;       //  6.29 MB
    hbf* wpb_t = (hbf*)ws; ws += (size_t)EMB * EMB * 2;     //  2.10 MB
    hbf* qh    = (hbf*)ws; ws += (size_t)MTOT * EMB * 2;    // 16.78 MB
    hbf* kh    = (hbf*)ws; ws += (size_t)MTOT * EMB * 2;    // 16.78 MB
    hbf* vh    = (hbf*)ws; ws += (size_t)MTOT * EMB * 2;    // 16.78 MB
    hbf* yb    = (hbf*)ws; ws += (size_t)MTOT * EMB * 2;    // 16.78 MB  (total ~92.3 MB)

    f32_to_bf16<<<(MTOT * KD + 255) / 256, 256, 0, stream>>>(x, xb, MTOT * KD);
    f32_to_bf16_T<<<(KD * N1 + 255) / 256, 256, 0, stream>>>(W_attn, wab_t, KD, N1);
    f32_to_bf16_T<<<(KD * EMB + 255) / 256, 256, 0, stream>>>(W_proj, wpb_t, KD, EMB);

    gemm_qkv<<<(MTOT / 16) * (N1 / 16) / 4, 256, 0, stream>>>(xb, wab_t, qh, kh, vh);
    attn<<<BB * NH * (TT / 16), 64, 0, stream>>>(qh, kh, vh, yb);
    gemm_out<<<(MTOT / 16) * (EMB / 16) / 4, 256, 0, stream>>>(yb, wpb_t, b_proj, out);
}

// Round 3
// 660.543 us; speedup vs baseline: 1.9341x; 1.9341x over previous
//
#include <hip/hip_runtime.h>
#include <hip/hip_bf16.h>

#define NH 16
#define HD 64
#define EMB 1024
#define BB 4
#define TT 2048
#define MTOT (BB*TT)        // 8192 rows
#define N1 (3*NH*HD)        // 3072
#define KD EMB              // 1024

#define BM 128
#define BN 128
#define BK 32

typedef __bf16 bf16x8 __attribute__((ext_vector_type(8)));
typedef float  f32x4  __attribute__((ext_vector_type(4)));
typedef __hip_bfloat16 hbf;

__device__ __forceinline__ void async_copy16(const hbf* g, hbf* l) {
    __builtin_amdgcn_global_load_lds(
        (const __attribute__((address_space(1))) void*)g,
        (__attribute__((address_space(3))) void*)l, 16, 0, 0);
}

// ---------------- conversion kernels ----------------

__global__ void f32_to_bf16(const float* __restrict__ in, hbf* __restrict__ out, int n) {
    int i = blockIdx.x * blockDim.x + threadIdx.x;
    if (i < n) out[i] = __float2bfloat16(in[i]);
}

// out[c*R + r] = in[r*C + c]  (transpose while converting)
__global__ void f32_to_bf16_T(const float* __restrict__ in, hbf* __restrict__ out, int R, int C) {
    int i = blockIdx.x * blockDim.x + threadIdx.x;
    if (i < R * C) {
        int r = i / C, c = i % C;
        out[(size_t)c * R + r] = __float2bfloat16(in[i]);
    }
}

// ---------------- tiled GEMM core (m97 structure) ----------------
// A [M,K] row-major bf16, Bt [N,K] row-major bf16.
// Block 256 thr = 4 waves; tile 128x128, BK=32; each wave computes 64x64
// (4x4 tiles of 16x16x32 MFMA). LDS tiles stored [row][32] contiguous
// (global_load_lds needs lane-contiguous order — no padding).

#define GEMM_STAGE(Sdst, Gsrc, ld)                                            \
    {                                                                         \
        _Pragma("unroll")                                                     \
        for (int q = 0; q < 2; ++q) {                                         \
            int e = q * 2048 + tid * 8;                                       \
            int row = e >> 5, col = e & 31;                                   \
            async_copy16(Gsrc + (size_t)row * (ld) + col,                     \
                         Sdst + q * 2048 + (tid & ~63) * 8);                  \
        }                                                                     \
    }

// ---------------- GEMM 1: qkv = x @ W_attn, scatter to q/k/vt ----------------

__global__ __launch_bounds__(256) void gemm_qkv(
    const hbf* __restrict__ A, const hbf* __restrict__ Bt,
    hbf* __restrict__ qh, hbf* __restrict__ kh, hbf* __restrict__ vt)
{
    __shared__ __align__(16) hbf As[BM * BK];
    __shared__ __align__(16) hbf Bs[BN * BK];
    int tid = threadIdx.x;
    int wv = tid >> 6, lane = tid & 63;
    int g = lane >> 4, c = lane & 15;
    int wr = wv >> 1, wc = wv & 1;
    int bn = blockIdx.x % (N1 / BN);
    int bm = blockIdx.x / (N1 / BN);
    int m0 = bm * BM, n0 = bn * BN;

    f32x4 acc[4][4];
    #pragma unroll
    for (int i = 0; i < 4; ++i)
        #pragma unroll
        for (int j = 0; j < 4; ++j) acc[i][j] = (f32x4){0.f, 0.f, 0.f, 0.f};

    for (int k0 = 0; k0 < KD; k0 += BK) {
        const hbf* Ag = A  + (size_t)m0 * KD + k0;
        const hbf* Bg = Bt + (size_t)n0 * KD + k0;
        GEMM_STAGE(As, Ag, KD);
        GEMM_STAGE(Bs, Bg, KD);
        __syncthreads();
        bf16x8 af[4], bf[4];
        #pragma unroll
        for (int mi = 0; mi < 4; ++mi)
            af[mi] = *(const bf16x8*)(As + (wr * 64 + mi * 16 + c) * BK + g * 8);
        #pragma unroll
        for (int ni = 0; ni < 4; ++ni)
            bf[ni] = *(const bf16x8*)(Bs + (wc * 64 + ni * 16 + c) * BK + g * 8);
        #pragma unroll
        for (int mi = 0; mi < 4; ++mi)
            #pragma unroll
            for (int ni = 0; ni < 4; ++ni)
                acc[mi][ni] = __builtin_amdgcn_mfma_f32_16x16x32_bf16(af[mi], bf[ni], acc[mi][ni], 0, 0, 0);
        __syncthreads();
    }

    // epilogue: which/h wave-uniform (64-wide n-range, 64|1024 aligned)
    int colbase = n0 + wc * 64;
    int which = colbase / (NH * HD);
    int h = (colbase % (NH * HD)) / HD;
    int b = m0 / TT;                       // 128-row tile within one batch
    float scale = (which == 0) ? 0.125f : 1.0f;
    if (which < 2) {
        hbf* dst = (which == 0) ? qh : kh;
        dst += ((size_t)b * NH + h) * TT * HD;
        #pragma unroll
        for (int mi = 0; mi < 4; ++mi)
            #pragma unroll
            for (int ni = 0; ni < 4; ++ni) {
                int d = ni * 16 + c;
                #pragma unroll
                for (int r = 0; r < 4; ++r) {
                    int t = (m0 + wr * 64 + mi * 16 + g * 4 + r) % TT;
                    dst[(size_t)t * HD + d] = __float2bfloat16(acc[mi][ni][r] * scale);
                }
            }
    } else {
        hbf* dst = vt + ((size_t)b * NH + h) * TT * HD;   // [HD][TT] per head
        #pragma unroll
        for (int mi = 0; mi < 4; ++mi)
            #pragma unroll
            for (int ni = 0; ni < 4; ++ni) {
                int d = ni * 16 + c;
                #pragma unroll
                for (int r = 0; r < 4; ++r) {
                    int t = (m0 + wr * 64 + mi * 16 + g * 4 + r) % TT;
                    dst[(size_t)d * TT + t] = __float2bfloat16(acc[mi][ni][r]);
                }
            }
    }
}

// ---------------- flash attention: 4 waves/block, 1 q-tile(16 rows)/wave ----------------

__global__ __launch_bounds__(256) void attn(
    const hbf* __restrict__ qh, const hbf* __restrict__ kh, const hbf* __restrict__ vt,
    hbf* __restrict__ y)   // [MTOT, EMB], col = h*HD + d
{
    __shared__ __align__(16) hbf P[4][16][32];
    int wv = threadIdx.x >> 6;
    int lane = threadIdx.x & 63;
    int g = lane >> 4, c = lane & 15;
    int tile = blockIdx.x * 4 + wv;
    int qt = tile & (TT / 16 - 1);
    int bh = tile >> 7;                    // TT/16 == 128
    int h = bh & (NH - 1);
    int b = bh >> 4;
    int t0 = qt * 16;

    const hbf* Q = qh + (size_t)bh * TT * HD;
    const hbf* K = kh + (size_t)bh * TT * HD;
    const hbf* V = vt + (size_t)bh * TT * HD;   // [HD][TT]

    bf16x8 aq0 = *(const bf16x8*)(Q + (size_t)(t0 + c) * HD + g * 8);
    bf16x8 aq1 = *(const bf16x8*)(Q + (size_t)(t0 + c) * HD + 32 + g * 8);

    float m_s[4], l_s[4];
    f32x4 o[4];
    #pragma unroll
    for (int r = 0; r < 4; ++r) { m_s[r] = -1e30f; l_s[r] = 0.f; }
    #pragma unroll
    for (int n = 0; n < 4; ++n) o[n] = (f32x4){0.f, 0.f, 0.f, 0.f};

    int kend = t0 + 16;
    for (int k0 = 0; k0 < kend; k0 += 32) {
        bf16x8 b00 = *(const bf16x8*)(K + (size_t)(k0 + c) * HD + g * 8);
        bf16x8 b01 = *(const bf16x8*)(K + (size_t)(k0 + c) * HD + 32 + g * 8);
        bf16x8 b10 = *(const bf16x8*)(K + (size_t)(k0 + 16 + c) * HD + g * 8);
        bf16x8 b11 = *(const bf16x8*)(K + (size_t)(k0 + 16 + c) * HD + 32 + g * 8);
        f32x4 s0 = {0.f, 0.f, 0.f, 0.f}, s1 = {0.f, 0.f, 0.f, 0.f};
        s0 = __builtin_amdgcn_mfma_f32_16x16x32_bf16(aq0, b00, s0, 0, 0, 0);
        s0 = __builtin_amdgcn_mfma_f32_16x16x32_bf16(aq1, b01, s0, 0, 0, 0);
        s1 = __builtin_amdgcn_mfma_f32_16x16x32_bf16(aq0, b10, s1, 0, 0, 0);
        s1 = __builtin_amdgcn_mfma_f32_16x16x32_bf16(aq1, b11, s1, 0, 0, 0);

        float p0[4], p1[4], alpha[4];
        #pragma unroll
        for (int r = 0; r < 4; ++r) {
            int row = t0 + g * 4 + r;
            float v0 = (k0 + c      <= row) ? s0[r] : -1e30f;
            float v1 = (k0 + 16 + c <= row) ? s1[r] : -1e30f;
            float mx = fmaxf(v0, v1);
            #pragma unroll
            for (int off = 1; off < 16; off <<= 1) mx = fmaxf(mx, __shfl_xor(mx, off));
            float mn = fmaxf(m_s[r], mx);
            float al = __expf(m_s[r] - mn);
            float e0 = __expf(v0 - mn);
            float e1 = __expf(v1 - mn);
            float sum = e0 + e1;
            #pragma unroll
            for (int off = 1; off < 16; off <<= 1) sum += __shfl_xor(sum, off);
            l_s[r] = l_s[r] * al + sum;
            m_s[r] = mn;
            alpha[r] = al;
            p0[r] = e0; p1[r] = e1;
        }
        #pragma unroll
        for (int n = 0; n < 4; ++n)
            #pragma unroll
            for (int r = 0; r < 4; ++r) o[n][r] *= alpha[r];

        // P (D-layout) -> LDS -> A-operand layout (per-wave buffer; within-wave
        // DS ops are in-order, compiler inserts the lgkmcnt wait)
        #pragma unroll
        for (int r = 0; r < 4; ++r) {
            P[wv][g * 4 + r][c]      = __float2bfloat16(p0[r]);
            P[wv][g * 4 + r][16 + c] = __float2bfloat16(p1[r]);
        }
        bf16x8 apf = *(const bf16x8*)(&P[wv][c][g * 8]);

        // O += P @ V ; V^T layout makes B-frag one 16B load
        #pragma unroll
        for (int n = 0; n < 4; ++n) {
            bf16x8 bv = *(const bf16x8*)(V + (size_t)(n * 16 + c) * TT + k0 + g * 8);
            o[n] = __builtin_amdgcn_mfma_f32_16x16x32_bf16(apf, bv, o[n], 0, 0, 0);
        }
    }

    #pragma unroll
    for (int n = 0; n < 4; ++n)
        #pragma unroll
        for (int r = 0; r < 4; ++r) {
            int row = t0 + g * 4 + r;
            float val = o[n][r] / l_s[r];
            size_t off = ((size_t)(b * TT + row)) * EMB + h * HD + n * 16 + c;
            y[off] = __float2bfloat16(val);
        }
}

// ---------------- GEMM 2: out = y @ W_proj + b_proj ----------------

__global__ __launch_bounds__(256) void gemm_out(
    const hbf* __restrict__ A, const hbf* __restrict__ Bt,
    const float* __restrict__ bias, float* __restrict__ out)
{
    __shared__ __align__(16) hbf As[BM * BK];
    __shared__ __align__(16) hbf Bs[BN * BK];
    int tid = threadIdx.x;
    int wv = tid >> 6, lane = tid & 63;
    int g = lane >> 4, c = lane & 15;
    int wr = wv >> 1, wc = wv & 1;
    int bn = blockIdx.x % (EMB / BN);
    int bm = blockIdx.x / (EMB / BN);
    int m0 = bm * BM, n0 = bn * BN;

    f32x4 acc[4][4];
    #pragma unroll
    for (int i = 0; i < 4; ++i)
        #pragma unroll
        for (int j = 0; j < 4; ++j) acc[i][j] = (f32x4){0.f, 0.f, 0.f, 0.f};

    for (int k0 = 0; k0 < EMB; k0 += BK) {
        const hbf* Ag = A  + (size_t)m0 * EMB + k0;
        const hbf* Bg = Bt + (size_t)n0 * EMB + k0;
        GEMM_STAGE(As, Ag, EMB);
        GEMM_STAGE(Bs, Bg, EMB);
        __syncthreads();
        bf16x8 af[4], bf[4];
        #pragma unroll
        for (int mi = 0; mi < 4; ++mi)
            af[mi] = *(const bf16x8*)(As + (wr * 64 + mi * 16 + c) * BK + g * 8);
        #pragma unroll
        for (int ni = 0; ni < 4; ++ni)
            bf[ni] = *(const bf16x8*)(Bs + (wc * 64 + ni * 16 + c) * BK + g * 8);
        #pragma unroll
        for (int mi = 0; mi < 4; ++mi)
            #pragma unroll
            for (int ni = 0; ni < 4; ++ni)
                acc[mi][ni] = __builtin_amdgcn_mfma_f32_16x16x32_bf16(af[mi], bf[ni], acc[mi][ni], 0, 0, 0);
        __syncthreads();
    }

    #pragma unroll
    for (int mi = 0; mi < 4; ++mi)
        #pragma unroll
        for (int ni = 0; ni < 4; ++ni) {
            int col = n0 + wc * 64 + ni * 16 + c;
            float bv = bias[col];
            #pragma unroll
            for (int r = 0; r < 4; ++r) {
                int row = m0 + wr * 64 + mi * 16 + g * 4 + r;
                out[(size_t)row * EMB + col] = acc[mi][ni][r] + bv;
            }
        }
}

// ---------------- launch ----------------

extern "C" void kernel_launch(void* const* d_in, const int* in_sizes, int n_in,
                              void* d_out, int out_size, void* d_ws, size_t ws_size,
                              hipStream_t stream)
{
    const float* x      = (const float*)d_in[0];
    const float* W_attn = (const float*)d_in[1];
    const float* W_proj = (const float*)d_in[2];
    const float* b_proj = (const float*)d_in[3];
    float* out = (float*)d_out;

    char* ws = (char*)d_ws;
    hbf* xb    = (hbf*)ws; ws += (size_t)MTOT * KD * 2;
    hbf* wab_t = (hbf*)ws; ws += (size_t)N1 * KD * 2;
    hbf* wpb_t = (hbf*)ws; ws += (size_t)EMB * EMB * 2;
    hbf* qh    = (hbf*)ws; ws += (size_t)MTOT * EMB * 2;
    hbf* kh    = (hbf*)ws; ws += (size_t)MTOT * EMB * 2;
    hbf* vt    = (hbf*)ws; ws += (size_t)MTOT * EMB * 2;   // transposed per head
    hbf* yb    = (hbf*)ws; ws += (size_t)MTOT * EMB * 2;

    f32_to_bf16<<<(MTOT * KD + 255) / 256, 256, 0, stream>>>(x, xb, MTOT * KD);
    f32_to_bf16_T<<<(KD * N1 + 255) / 256, 256, 0, stream>>>(W_attn, wab_t, KD, N1);
    f32_to_bf16_T<<<(KD * EMB + 255) / 256, 256, 0, stream>>>(W_proj, wpb_t, KD, EMB);

    gemm_qkv<<<(MTOT / BM) * (N1 / BN), 256, 0, stream>>>(xb, wab_t, qh, kh, vt);
    attn<<<BB * NH * (TT / 16) / 4, 256, 0, stream>>>(qh, kh, vt, yb);
    gemm_out<<<(MTOT / BM) * (EMB / BN), 256, 0, stream>>>(yb, wpb_t, b_proj, out);
}

// Round 4
// 458.690 us; speedup vs baseline: 2.7852x; 1.4401x over previous
//
#include <hip/hip_runtime.h>
#include <hip/hip_bf16.h>

#define NH 16
#define HD 64
#define EMB 1024
#define BB 4
#define TT 2048
#define MTOT (BB*TT)        // 8192 rows
#define N1 (3*NH*HD)        // 3072
#define KD EMB              // 1024

#define BM 128
#define BN 128
#define BK 32

#define PSTR 136            // LDS P row stride (hbf) — phase-conflict-free b128 reads

typedef __bf16 bf16x8 __attribute__((ext_vector_type(8)));
typedef __bf16 bf16x4 __attribute__((ext_vector_type(4)));
typedef float  f32x4  __attribute__((ext_vector_type(4)));
typedef __hip_bfloat16 hbf;

__device__ __forceinline__ void async_copy16(const hbf* g, hbf* l) {
    __builtin_amdgcn_global_load_lds(
        (const __attribute__((address_space(1))) void*)g,
        (__attribute__((address_space(3))) void*)l, 16, 0, 0);
}

__device__ __forceinline__ bf16x4 pack4(float x0, float x1, float x2, float x3) {
    union { bf16x4 v; hbf a[4]; } u;
    u.a[0] = __float2bfloat16(x0);
    u.a[1] = __float2bfloat16(x1);
    u.a[2] = __float2bfloat16(x2);
    u.a[3] = __float2bfloat16(x3);
    return u.v;
}

// ---------------- conversion kernels ----------------

__global__ void f32_to_bf16(const float* __restrict__ in, hbf* __restrict__ out, int n) {
    int i = blockIdx.x * blockDim.x + threadIdx.x;
    if (i < n) out[i] = __float2bfloat16(in[i]);
}

__global__ void f32_to_bf16_T(const float* __restrict__ in, hbf* __restrict__ out, int R, int C) {
    int i = blockIdx.x * blockDim.x + threadIdx.x;
    if (i < R * C) {
        int r = i / C, c = i % C;
        out[(size_t)c * R + r] = __float2bfloat16(in[i]);
    }
}

// ---------------- tiled GEMM core (m97 structure) — unchanged from R3 ----------------

#define GEMM_STAGE(Sdst, Gsrc, ld)                                            \
    {                                                                         \
        _Pragma("unroll")                                                     \
        for (int q = 0; q < 2; ++q) {                                         \
            int e = q * 2048 + tid * 8;                                       \
            int row = e >> 5, col = e & 31;                                   \
            async_copy16(Gsrc + (size_t)row * (ld) + col,                     \
                         Sdst + q * 2048 + (tid & ~63) * 8);                  \
        }                                                                     \
    }

__global__ __launch_bounds__(256) void gemm_qkv(
    const hbf* __restrict__ A, const hbf* __restrict__ Bt,
    hbf* __restrict__ qh, hbf* __restrict__ kh, hbf* __restrict__ vt)
{
    __shared__ __align__(16) hbf As[BM * BK];
    __shared__ __align__(16) hbf Bs[BN * BK];
    int tid = threadIdx.x;
    int wv = tid >> 6, lane = tid & 63;
    int g = lane >> 4, c = lane & 15;
    int wr = wv >> 1, wc = wv & 1;
    int bn = blockIdx.x % (N1 / BN);
    int bm = blockIdx.x / (N1 / BN);
    int m0 = bm * BM, n0 = bn * BN;

    f32x4 acc[4][4];
    #pragma unroll
    for (int i = 0; i < 4; ++i)
        #pragma unroll
        for (int j = 0; j < 4; ++j) acc[i][j] = (f32x4){0.f, 0.f, 0.f, 0.f};

    for (int k0 = 0; k0 < KD; k0 += BK) {
        const hbf* Ag = A  + (size_t)m0 * KD + k0;
        const hbf* Bg = Bt + (size_t)n0 * KD + k0;
        GEMM_STAGE(As, Ag, KD);
        GEMM_STAGE(Bs, Bg, KD);
        __syncthreads();
        bf16x8 af[4], bf[4];
        #pragma unroll
        for (int mi = 0; mi < 4; ++mi)
            af[mi] = *(const bf16x8*)(As + (wr * 64 + mi * 16 + c) * BK + g * 8);
        #pragma unroll
        for (int ni = 0; ni < 4; ++ni)
            bf[ni] = *(const bf16x8*)(Bs + (wc * 64 + ni * 16 + c) * BK + g * 8);
        #pragma unroll
        for (int mi = 0; mi < 4; ++mi)
            #pragma unroll
            for (int ni = 0; ni < 4; ++ni)
                acc[mi][ni] = __builtin_amdgcn_mfma_f32_16x16x32_bf16(af[mi], bf[ni], acc[mi][ni], 0, 0, 0);
        __syncthreads();
    }

    int colbase = n0 + wc * 64;
    int which = colbase / (NH * HD);
    int h = (colbase % (NH * HD)) / HD;
    int b = m0 / TT;
    float scale = (which == 0) ? 0.125f : 1.0f;
    if (which < 2) {
        hbf* dst = (which == 0) ? qh : kh;
        dst += ((size_t)b * NH + h) * TT * HD;
        #pragma unroll
        for (int mi = 0; mi < 4; ++mi)
            #pragma unroll
            for (int ni = 0; ni < 4; ++ni) {
                int d = ni * 16 + c;
                #pragma unroll
                for (int r = 0; r < 4; ++r) {
                    int t = (m0 + wr * 64 + mi * 16 + g * 4 + r) % TT;
                    dst[(size_t)t * HD + d] = __float2bfloat16(acc[mi][ni][r] * scale);
                }
            }
    } else {
        hbf* dst = vt + ((size_t)b * NH + h) * TT * HD;   // [HD][TT] per head
        #pragma unroll
        for (int mi = 0; mi < 4; ++mi)
            #pragma unroll
            for (int ni = 0; ni < 4; ++ni) {
                int d = ni * 16 + c;
                #pragma unroll
                for (int r = 0; r < 4; ++r) {
                    int t = (m0 + wr * 64 + mi * 16 + g * 4 + r) % TT;
                    dst[(size_t)d * TT + t] = __float2bfloat16(acc[mi][ni][r]);
                }
            }
    }
}

// ---------------- flash attention, S^T formulation ----------------
// One wave handles one 16-row q-tile, 128 keys per online-softmax step.
// S^T = K·Q^T: D row = key (g*4+r), col = q-row (c) → softmax reduce is
// in-lane + 2 shuffles. O^T = V^T·P^T accumulated directly by MFMA.

__device__ __attribute__((noinline)) void attn_tile(
    const hbf* __restrict__ Q, const hbf* __restrict__ K, const hbf* __restrict__ V,
    hbf* __restrict__ y, hbf* __restrict__ Pw,
    int t0, int g, int c, int b, int h)
{
    // B-operand (Q^T): b[j] = Q[t0+c][k] — same 16B loads as before
    bf16x8 aq0 = *(const bf16x8*)(Q + (size_t)(t0 + c) * HD + g * 8);
    bf16x8 aq1 = *(const bf16x8*)(Q + (size_t)(t0 + c) * HD + 32 + g * 8);

    float m = -1e30f, l = 0.f;
    f32x4 o[4];
    #pragma unroll
    for (int d = 0; d < 4; ++d) o[d] = (f32x4){0.f, 0.f, 0.f, 0.f};

    const int kend = t0 + 16;
    for (int k0 = 0; k0 < kend; k0 += 128) {
        f32x4 s[8];
        // S^T subtiles: rows = keys k0+16t+g*4+r, col = q-row t0+c
        #pragma unroll
        for (int t = 0; t < 8; ++t) {
            if (k0 + 16 * t < kend) {                 // wave-uniform
                const hbf* kp = K + (size_t)(k0 + 16 * t + c) * HD;
                bf16x8 kf0 = *(const bf16x8*)(kp + g * 8);
                bf16x8 kf1 = *(const bf16x8*)(kp + 32 + g * 8);
                f32x4 acc = (f32x4){0.f, 0.f, 0.f, 0.f};
                acc = __builtin_amdgcn_mfma_f32_16x16x32_bf16(kf0, aq0, acc, 0, 0, 0);
                acc = __builtin_amdgcn_mfma_f32_16x16x32_bf16(kf1, aq1, acc, 0, 0, 0);
                if (k0 + 16 * t == t0) {              // diagonal subtile: key≤q ⇔ g*4+r≤c
                    #pragma unroll
                    for (int r = 0; r < 4; ++r)
                        acc[r] = (g * 4 + r <= c) ? acc[r] : -1e30f;
                }
                s[t] = acc;
            }
        }
        // online softmax: in-lane reduce over keys, 2 shuffles across g-groups
        f32x4 vmax = s[0];
        #pragma unroll
        for (int t = 1; t < 8; ++t)
            if (k0 + 16 * t < kend) {
                #pragma unroll
                for (int r = 0; r < 4; ++r) vmax[r] = fmaxf(vmax[r], s[t][r]);
            }
        float mx = fmaxf(fmaxf(vmax[0], vmax[1]), fmaxf(vmax[2], vmax[3]));
        mx = fmaxf(mx, __shfl_xor(mx, 16));
        mx = fmaxf(mx, __shfl_xor(mx, 32));
        float mn = fmaxf(m, mx);
        float al = __expf(m - mn);
        m = mn;

        f32x4 vsum = (f32x4){0.f, 0.f, 0.f, 0.f};
        #pragma unroll
        for (int t = 0; t < 8; ++t) {
            if (k0 + 16 * t < kend) {
                #pragma unroll
                for (int r = 0; r < 4; ++r) s[t][r] = __expf(s[t][r] - mn);
                vsum += s[t];
                // P^T → LDS transposed: P[q=c][key 16t+g*4..+3], one b64 write
                *(bf16x4*)(Pw + c * PSTR + t * 16 + g * 4) =
                    pack4(s[t][0], s[t][1], s[t][2], s[t][3]);
            } else if (k0 + 16 * t == kend && (t & 1)) {
                // odd subtile count: zero-pad partner subtile of last PV chunk
                *(bf16x4*)(Pw + c * PSTR + t * 16 + g * 4) = pack4(0.f, 0.f, 0.f, 0.f);
            }
        }
        float sum = vsum[0] + vsum[1] + vsum[2] + vsum[3];
        sum += __shfl_xor(sum, 16);
        sum += __shfl_xor(sum, 32);
        l = l * al + sum;
        #pragma unroll
        for (int d = 0; d < 4; ++d)
            #pragma unroll
            for (int r = 0; r < 4; ++r) o[d][r] *= al;

        // O^T += V^T · P^T  (A = vt rows d, B = P^T from LDS, contiguous b128)
        #pragma unroll
        for (int sc = 0; sc < 4; ++sc) {
            if (k0 + 32 * sc < kend) {                // wave-uniform
                bf16x8 pf = *(const bf16x8*)(Pw + c * PSTR + sc * 32 + g * 8);
                #pragma unroll
                for (int d = 0; d < 4; ++d) {
                    bf16x8 vf = *(const bf16x8*)(V + (size_t)(d * 16 + c) * TT + k0 + sc * 32 + g * 8);
                    o[d] = __builtin_amdgcn_mfma_f32_16x16x32_bf16(vf, pf, o[d], 0, 0, 0);
                }
            }
        }
    }

    float inv = 1.0f / l;
    #pragma unroll
    for (int d = 0; d < 4; ++d) {
        // O^T: lane holds dims dtile*16+g*4..+3 of q-row t0+c → one b64 store
        *(bf16x4*)(y + (size_t)(b * TT + t0 + c) * EMB + h * HD + d * 16 + g * 4) =
            pack4(o[d][0] * inv, o[d][1] * inv, o[d][2] * inv, o[d][3] * inv);
    }
}

__global__ __launch_bounds__(256, 4) void attn(
    const hbf* __restrict__ qh, const hbf* __restrict__ kh, const hbf* __restrict__ vt,
    hbf* __restrict__ y)
{
    __shared__ __align__(16) hbf P[4][16 * PSTR];
    int wv = threadIdx.x >> 6, lane = threadIdx.x & 63;
    int g = lane >> 4, c = lane & 15;
    int wid = blockIdx.x * 4 + wv;
    int bh = wid >> 6;              // 64 pair-slots per (b,h)
    int pr = wid & 63;
    int b = bh >> 4, h = bh & 15;
    const hbf* Q = qh + (size_t)bh * TT * HD;
    const hbf* K = kh + (size_t)bh * TT * HD;
    const hbf* V = vt + (size_t)bh * TT * HD;
    hbf* Pw = &P[wv][0];
    // complementary pair: total keys per wave = (16pr+16)+(16(127-pr)+16) = const
    attn_tile(Q, K, V, y, Pw, pr * 16, g, c, b, h);
    attn_tile(Q, K, V, y, Pw, (127 - pr) * 16, g, c, b, h);
}

// ---------------- GEMM 2: out = y @ W_proj + b_proj — unchanged from R3 ----------------

__global__ __launch_bounds__(256) void gemm_out(
    const hbf* __restrict__ A, const hbf* __restrict__ Bt,
    const float* __restrict__ bias, float* __restrict__ out)
{
    __shared__ __align__(16) hbf As[BM * BK];
    __shared__ __align__(16) hbf Bs[BN * BK];
    int tid = threadIdx.x;
    int wv = tid >> 6, lane = tid & 63;
    int g = lane >> 4, c = lane & 15;
    int wr = wv >> 1, wc = wv & 1;
    int bn = blockIdx.x % (EMB / BN);
    int bm = blockIdx.x / (EMB / BN);
    int m0 = bm * BM, n0 = bn * BN;

    f32x4 acc[4][4];
    #pragma unroll
    for (int i = 0; i < 4; ++i)
        #pragma unroll
        for (int j = 0; j < 4; ++j) acc[i][j] = (f32x4){0.f, 0.f, 0.f, 0.f};

    for (int k0 = 0; k0 < EMB; k0 += BK) {
        const hbf* Ag = A  + (size_t)m0 * EMB + k0;
        const hbf* Bg = Bt + (size_t)n0 * EMB + k0;
        GEMM_STAGE(As, Ag, EMB);
        GEMM_STAGE(Bs, Bg, EMB);
        __syncthreads();
        bf16x8 af[4], bf[4];
        #pragma unroll
        for (int mi = 0; mi < 4; ++mi)
            af[mi] = *(const bf16x8*)(As + (wr * 64 + mi * 16 + c) * BK + g * 8);
        #pragma unroll
        for (int ni = 0; ni < 4; ++ni)
            bf[ni] = *(const bf16x8*)(Bs + (wc * 64 + ni * 16 + c) * BK + g * 8);
        #pragma unroll
        for (int mi = 0; mi < 4; ++mi)
            #pragma unroll
            for (int ni = 0; ni < 4; ++ni)
                acc[mi][ni] = __builtin_amdgcn_mfma_f32_16x16x32_bf16(af[mi], bf[ni], acc[mi][ni], 0, 0, 0);
        __syncthreads();
    }

    #pragma unroll
    for (int mi = 0; mi < 4; ++mi)
        #pragma unroll
        for (int ni = 0; ni < 4; ++ni) {
            int col = n0 + wc * 64 + ni * 16 + c;
            float bv = bias[col];
            #pragma unroll
            for (int r = 0; r < 4; ++r) {
                int row = m0 + wr * 64 + mi * 16 + g * 4 + r;
                out[(size_t)row * EMB + col] = acc[mi][ni][r] + bv;
            }
        }
}

// ---------------- launch ----------------

extern "C" void kernel_launch(void* const* d_in, const int* in_sizes, int n_in,
                              void* d_out, int out_size, void* d_ws, size_t ws_size,
                              hipStream_t stream)
{
    const float* x      = (const float*)d_in[0];
    const float* W_attn = (const float*)d_in[1];
    const float* W_proj = (const float*)d_in[2];
    const float* b_proj = (const float*)d_in[3];
    float* out = (float*)d_out;

    char* ws = (char*)d_ws;
    hbf* xb    = (hbf*)ws; ws += (size_t)MTOT * KD * 2;
    hbf* wab_t = (hbf*)ws; ws += (size_t)N1 * KD * 2;
    hbf* wpb_t = (hbf*)ws; ws += (size_t)EMB * EMB * 2;
    hbf* qh    = (hbf*)ws; ws += (size_t)MTOT * EMB * 2;
    hbf* kh    = (hbf*)ws; ws += (size_t)MTOT * EMB * 2;
    hbf* vt    = (hbf*)ws; ws += (size_t)MTOT * EMB * 2;
    hbf* yb    = (hbf*)ws; ws += (size_t)MTOT * EMB * 2;

    f32_to_bf16<<<(MTOT * KD + 255) / 256, 256, 0, stream>>>(x, xb, MTOT * KD);
    f32_to_bf16_T<<<(KD * N1 + 255) / 256, 256, 0, stream>>>(W_attn, wab_t, KD, N1);
    f32_to_bf16_T<<<(KD * EMB + 255) / 256, 256, 0, stream>>>(W_proj, wpb_t, KD, EMB);

    gemm_qkv<<<(MTOT / BM) * (N1 / BN), 256, 0, stream>>>(xb, wab_t, qh, kh, vt);
    attn<<<BB * NH * 64 / 4, 256, 0, stream>>>(qh, kh, vt, yb);
    gemm_out<<<(MTOT / BM) * (EMB / BN), 256, 0, stream>>>(yb, wpb_t, b_proj, out);
}

// Round 5
// 290.004 us; speedup vs baseline: 4.4052x; 1.5817x over previous
//
#include <hip/hip_runtime.h>
#include <hip/hip_bf16.h>

#define NH 16
#define HD 64
#define EMB 1024
#define BB 4
#define TT 2048
#define MTOT (BB*TT)        // 8192 rows
#define N1 (3*NH*HD)        // 3072
#define KD EMB              // 1024

#define BM 128
#define BN 128
#define BK 32

typedef __bf16 bf16x8 __attribute__((ext_vector_type(8)));
typedef __bf16 bf16x4 __attribute__((ext_vector_type(4)));
typedef float  f32x4  __attribute__((ext_vector_type(4)));
typedef __hip_bfloat16 hbf;

__device__ __forceinline__ void async_copy16(const hbf* g, hbf* l) {
    __builtin_amdgcn_global_load_lds(
        (const __attribute__((address_space(1))) void*)g,
        (__attribute__((address_space(3))) void*)l, 16, 0, 0);
}

__device__ __forceinline__ bf16x4 pack4(float x0, float x1, float x2, float x3) {
    union { bf16x4 v; hbf a[4]; } u;
    u.a[0] = __float2bfloat16(x0);
    u.a[1] = __float2bfloat16(x1);
    u.a[2] = __float2bfloat16(x2);
    u.a[3] = __float2bfloat16(x3);
    return u.v;
}

// ---------------- conversion kernels ----------------

__global__ void f32_to_bf16(const float* __restrict__ in, hbf* __restrict__ out, int n) {
    int i = blockIdx.x * blockDim.x + threadIdx.x;
    if (i < n) out[i] = __float2bfloat16(in[i]);
}

__global__ void f32_to_bf16_T(const float* __restrict__ in, hbf* __restrict__ out, int R, int C) {
    int i = blockIdx.x * blockDim.x + threadIdx.x;
    if (i < R * C) {
        int r = i / C, c = i % C;
        out[(size_t)c * R + r] = __float2bfloat16(in[i]);
    }
}

// ---------------- tiled GEMM core (m97 structure) — unchanged ----------------

#define GEMM_STAGE(Sdst, Gsrc, ld)                                            \
    {                                                                         \
        _Pragma("unroll")                                                     \
        for (int q = 0; q < 2; ++q) {                                         \
            int e = q * 2048 + tid * 8;                                       \
            int row = e >> 5, col = e & 31;                                   \
            async_copy16(Gsrc + (size_t)row * (ld) + col,                     \
                         Sdst + q * 2048 + (tid & ~63) * 8);                  \
        }                                                                     \
    }

__global__ __launch_bounds__(256) void gemm_qkv(
    const hbf* __restrict__ A, const hbf* __restrict__ Bt,
    hbf* __restrict__ qh, hbf* __restrict__ kh, hbf* __restrict__ vt)
{
    __shared__ __align__(16) hbf As[BM * BK];
    __shared__ __align__(16) hbf Bs[BN * BK];
    int tid = threadIdx.x;
    int wv = tid >> 6, lane = tid & 63;
    int g = lane >> 4, c = lane & 15;
    int wr = wv >> 1, wc = wv & 1;
    int bn = blockIdx.x % (N1 / BN);
    int bm = blockIdx.x / (N1 / BN);
    int m0 = bm * BM, n0 = bn * BN;

    f32x4 acc[4][4];
    #pragma unroll
    for (int i = 0; i < 4; ++i)
        #pragma unroll
        for (int j = 0; j < 4; ++j) acc[i][j] = (f32x4){0.f, 0.f, 0.f, 0.f};

    for (int k0 = 0; k0 < KD; k0 += BK) {
        const hbf* Ag = A  + (size_t)m0 * KD + k0;
        const hbf* Bg = Bt + (size_t)n0 * KD + k0;
        GEMM_STAGE(As, Ag, KD);
        GEMM_STAGE(Bs, Bg, KD);
        __syncthreads();
        bf16x8 af[4], bf[4];
        #pragma unroll
        for (int mi = 0; mi < 4; ++mi)
            af[mi] = *(const bf16x8*)(As + (wr * 64 + mi * 16 + c) * BK + g * 8);
        #pragma unroll
        for (int ni = 0; ni < 4; ++ni)
            bf[ni] = *(const bf16x8*)(Bs + (wc * 64 + ni * 16 + c) * BK + g * 8);
        #pragma unroll
        for (int mi = 0; mi < 4; ++mi)
            #pragma unroll
            for (int ni = 0; ni < 4; ++ni)
                acc[mi][ni] = __builtin_amdgcn_mfma_f32_16x16x32_bf16(af[mi], bf[ni], acc[mi][ni], 0, 0, 0);
        __syncthreads();
    }

    int colbase = n0 + wc * 64;
    int which = colbase / (NH * HD);
    int h = (colbase % (NH * HD)) / HD;
    int b = m0 / TT;
    float scale = (which == 0) ? 0.125f : 1.0f;
    if (which < 2) {
        hbf* dst = (which == 0) ? qh : kh;
        dst += ((size_t)b * NH + h) * TT * HD;
        #pragma unroll
        for (int mi = 0; mi < 4; ++mi)
            #pragma unroll
            for (int ni = 0; ni < 4; ++ni) {
                int d = ni * 16 + c;
                #pragma unroll
                for (int r = 0; r < 4; ++r) {
                    int t = (m0 + wr * 64 + mi * 16 + g * 4 + r) % TT;
                    dst[(size_t)t * HD + d] = __float2bfloat16(acc[mi][ni][r] * scale);
                }
            }
    } else {
        hbf* dst = vt + ((size_t)b * NH + h) * TT * HD;   // [HD][TT] per head
        #pragma unroll
        for (int mi = 0; mi < 4; ++mi)
            #pragma unroll
            for (int ni = 0; ni < 4; ++ni) {
                int d = ni * 16 + c;
                #pragma unroll
                for (int r = 0; r < 4; ++r) {
                    int t = (m0 + wr * 64 + mi * 16 + g * 4 + r) % TT;
                    dst[(size_t)d * TT + t] = __float2bfloat16(acc[mi][ni][r]);
                }
            }
    }
}

// ---------------- flash attention v3: LDS-staged K/V, S^T formulation ----------------
// Block = 4 waves x 32 q-rows = 128-q supertile. Per 64-key step: stage
// K[64x64] and V^T[64x64] into LDS (global_load_lds, XOR-swizzled source so
// all ds_read_b128 are 2-way/free). Each wave: two 16-q tiles sharing K/V
// fragments. Causal balance: block handles supertile pair (s, 15-s).

__global__ __launch_bounds__(256, 2) void attn(
    const hbf* __restrict__ qh, const hbf* __restrict__ kh, const hbf* __restrict__ vt,
    hbf* __restrict__ y)
{
    __shared__ __align__(16) hbf Ks[64 * 64];       // [key][dblk swizzled]
    __shared__ __align__(16) hbf Vs[64 * 64];       // [dim][kb swizzled]
    __shared__ __align__(16) hbf Ps[4][2][16 * 64]; // per wave, per q-tile

    int tid = threadIdx.x;
    int wv = tid >> 6, lane = tid & 63;
    int g = lane >> 4, c = lane & 15;
    int c7 = c & 7;

    int bh = blockIdx.x >> 3;       // 8 supertile-pairs per (b,h)
    int pi = blockIdx.x & 7;
    int b = bh >> 4, h = bh & 15;

    const hbf* Q = qh + (size_t)bh * TT * HD;
    const hbf* K = kh + (size_t)bh * TT * HD;
    const hbf* V = vt + (size_t)bh * TT * HD;   // [HD][TT]

    #pragma unroll
    for (int pass = 0; pass < 2; ++pass) {
        int sst = pass ? (15 - pi) : pi;
        int qb = sst * 128;
        int qA = qb + wv * 32;
        int qB = qA + 16;
        int kendA = qA + 16, kendB = qA + 32;
        int kmax = qb + 128;

        // Q fragments (B-operand) for both q-tiles
        bf16x8 aqA0 = *(const bf16x8*)(Q + (size_t)(qA + c) * HD + g * 8);
        bf16x8 aqA1 = *(const bf16x8*)(Q + (size_t)(qA + c) * HD + 32 + g * 8);
        bf16x8 aqB0 = *(const bf16x8*)(Q + (size_t)(qB + c) * HD + g * 8);
        bf16x8 aqB1 = *(const bf16x8*)(Q + (size_t)(qB + c) * HD + 32 + g * 8);

        float m_s[2] = {-1e30f, -1e30f}, l_s[2] = {0.f, 0.f};
        f32x4 o[2][4];
        #pragma unroll
        for (int qi = 0; qi < 2; ++qi)
            #pragma unroll
            for (int d = 0; d < 4; ++d) o[qi][d] = (f32x4){0.f, 0.f, 0.f, 0.f};

        for (int k0 = 0; k0 < kmax; k0 += 64) {
            __syncthreads();   // prior step's LDS reads complete before overwrite
            // stage K tile: LDS[key][sblk] = K[k0+key][(sblk^(key&7))*8..]
            #pragma unroll
            for (int it = 0; it < 2; ++it) {
                int e = it * 2048 + tid * 8;
                int key = e >> 6, sblk = (e >> 3) & 7;
                int dblk = sblk ^ (key & 7);
                async_copy16(K + (size_t)(k0 + key) * HD + dblk * 8,
                             Ks + it * 2048 + (tid & ~63) * 8);
            }
            // stage V tile: LDS[dim][sblk] = V[dim][k0 + (sblk^(dim&7))*8..]
            #pragma unroll
            for (int it = 0; it < 2; ++it) {
                int e = it * 2048 + tid * 8;
                int dim = e >> 6, sblk = (e >> 3) & 7;
                int kb = sblk ^ (dim & 7);
                async_copy16(V + (size_t)dim * TT + k0 + kb * 8,
                             Vs + it * 2048 + (tid & ~63) * 8);
            }
            __syncthreads();   // staged

            if (k0 < kendB) {
                // ---- S^T = K·Q^T for both q-tiles (K fragments shared) ----
                f32x4 s[2][4];
                #pragma unroll
                for (int t = 0; t < 4; ++t) {
                    int kt = k0 + 16 * t;
                    if (kt < kendB) {                       // wave-uniform
                        int rb = (16 * t + c) * 64;
                        bf16x8 kf0 = *(const bf16x8*)(Ks + rb + ((g ^ c7) << 3));
                        bf16x8 kf1 = *(const bf16x8*)(Ks + rb + (((4 + g) ^ c7) << 3));
                        if (kt < kendA) {
                            f32x4 a0 = (f32x4){0.f, 0.f, 0.f, 0.f};
                            a0 = __builtin_amdgcn_mfma_f32_16x16x32_bf16(kf0, aqA0, a0, 0, 0, 0);
                            a0 = __builtin_amdgcn_mfma_f32_16x16x32_bf16(kf1, aqA1, a0, 0, 0, 0);
                            if (kt == qA) {
                                #pragma unroll
                                for (int r = 0; r < 4; ++r)
                                    a0[r] = (g * 4 + r <= c) ? a0[r] : -1e30f;
                            }
                            s[0][t] = a0;
                        } else
                            s[0][t] = (f32x4){-1e30f, -1e30f, -1e30f, -1e30f};
                        f32x4 a1 = (f32x4){0.f, 0.f, 0.f, 0.f};
                        a1 = __builtin_amdgcn_mfma_f32_16x16x32_bf16(kf0, aqB0, a1, 0, 0, 0);
                        a1 = __builtin_amdgcn_mfma_f32_16x16x32_bf16(kf1, aqB1, a1, 0, 0, 0);
                        if (kt == qB) {
                            #pragma unroll
                            for (int r = 0; r < 4; ++r)
                                a1[r] = (g * 4 + r <= c) ? a1[r] : -1e30f;
                        }
                        s[1][t] = a1;
                    } else {
                        s[0][t] = (f32x4){-1e30f, -1e30f, -1e30f, -1e30f};
                        s[1][t] = (f32x4){-1e30f, -1e30f, -1e30f, -1e30f};
                    }
                }
                // ---- online softmax per q-tile ----
                #pragma unroll
                for (int qi = 0; qi < 2; ++qi) {
                    int kend = qi ? kendB : kendA;
                    if (k0 < kend) {                        // wave-uniform
                        f32x4 vmax = s[qi][0];
                        #pragma unroll
                        for (int t = 1; t < 4; ++t)
                            #pragma unroll
                            for (int r = 0; r < 4; ++r)
                                vmax[r] = fmaxf(vmax[r], s[qi][t][r]);
                        float mx = fmaxf(fmaxf(vmax[0], vmax[1]), fmaxf(vmax[2], vmax[3]));
                        mx = fmaxf(mx, __shfl_xor(mx, 16));
                        mx = fmaxf(mx, __shfl_xor(mx, 32));
                        float mn = fmaxf(m_s[qi], mx);
                        float al = __expf(m_s[qi] - mn);
                        m_s[qi] = mn;
                        f32x4 vsum = (f32x4){0.f, 0.f, 0.f, 0.f};
                        hbf* Pq = &Ps[wv][qi][0];
                        #pragma unroll
                        for (int t = 0; t < 4; ++t) {
                            f32x4 e;
                            #pragma unroll
                            for (int r = 0; r < 4; ++r) e[r] = __expf(s[qi][t][r] - mn);
                            vsum += e;
                            // P^T swizzled write: one b64
                            *(bf16x4*)(Pq + c * 64 + (((2 * t + (g >> 1)) ^ c7) << 3) + ((g & 1) << 2)) =
                                pack4(e[0], e[1], e[2], e[3]);
                        }
                        float sum = vsum[0] + vsum[1] + vsum[2] + vsum[3];
                        sum += __shfl_xor(sum, 16);
                        sum += __shfl_xor(sum, 32);
                        l_s[qi] = l_s[qi] * al + sum;
                        #pragma unroll
                        for (int d = 0; d < 4; ++d)
                            #pragma unroll
                            for (int r = 0; r < 4; ++r) o[qi][d][r] *= al;
                    }
                }
                // ---- O^T += V^T·P^T (V fragments shared across q-tiles) ----
                #pragma unroll
                for (int sc = 0; sc < 2; ++sc) {
                    int kc = k0 + 32 * sc;
                    if (kc < kendB) {                       // wave-uniform
                        bool lA = kc < kendA;
                        bf16x8 pfB = *(const bf16x8*)(&Ps[wv][1][0] + c * 64 + (((4 * sc + g) ^ c7) << 3));
                        bf16x8 pfA;
                        if (lA)
                            pfA = *(const bf16x8*)(&Ps[wv][0][0] + c * 64 + (((4 * sc + g) ^ c7) << 3));
                        #pragma unroll
                        for (int d = 0; d < 4; ++d) {
                            int dim = d * 16 + c;
                            bf16x8 vf = *(const bf16x8*)(Vs + dim * 64 + (((4 * sc + g) ^ c7) << 3));
                            if (lA)
                                o[0][d] = __builtin_amdgcn_mfma_f32_16x16x32_bf16(vf, pfA, o[0][d], 0, 0, 0);
                            o[1][d] = __builtin_amdgcn_mfma_f32_16x16x32_bf16(vf, pfB, o[1][d], 0, 0, 0);
                        }
                    }
                }
            }
        }

        // epilogue: O^T lane holds dims d*16+g*4..+3 of q-row q0+c
        #pragma unroll
        for (int qi = 0; qi < 2; ++qi) {
            int q0 = qA + qi * 16;
            float inv = 1.0f / l_s[qi];
            #pragma unroll
            for (int d = 0; d < 4; ++d) {
                *(bf16x4*)(y + (size_t)(b * TT + q0 + c) * EMB + h * HD + d * 16 + g * 4) =
                    pack4(o[qi][d][0] * inv, o[qi][d][1] * inv,
                          o[qi][d][2] * inv, o[qi][d][3] * inv);
            }
        }
    }
}

// ---------------- GEMM 2: out = y @ W_proj + b_proj — unchanged ----------------

__global__ __launch_bounds__(256) void gemm_out(
    const hbf* __restrict__ A, const hbf* __restrict__ Bt,
    const float* __restrict__ bias, float* __restrict__ out)
{
    __shared__ __align__(16) hbf As[BM * BK];
    __shared__ __align__(16) hbf Bs[BN * BK];
    int tid = threadIdx.x;
    int wv = tid >> 6, lane = tid & 63;
    int g = lane >> 4, c = lane & 15;
    int wr = wv >> 1, wc = wv & 1;
    int bn = blockIdx.x % (EMB / BN);
    int bm = blockIdx.x / (EMB / BN);
    int m0 = bm * BM, n0 = bn * BN;

    f32x4 acc[4][4];
    #pragma unroll
    for (int i = 0; i < 4; ++i)
        #pragma unroll
        for (int j = 0; j < 4; ++j) acc[i][j] = (f32x4){0.f, 0.f, 0.f, 0.f};

    for (int k0 = 0; k0 < EMB; k0 += BK) {
        const hbf* Ag = A  + (size_t)m0 * EMB + k0;
        const hbf* Bg = Bt + (size_t)n0 * EMB + k0;
        GEMM_STAGE(As, Ag, EMB);
        GEMM_STAGE(Bs, Bg, EMB);
        __syncthreads();
        bf16x8 af[4], bf[4];
        #pragma unroll
        for (int mi = 0; mi < 4; ++mi)
            af[mi] = *(const bf16x8*)(As + (wr * 64 + mi * 16 + c) * BK + g * 8);
        #pragma unroll
        for (int ni = 0; ni < 4; ++ni)
            bf[ni] = *(const bf16x8*)(Bs + (wc * 64 + ni * 16 + c) * BK + g * 8);
        #pragma unroll
        for (int mi = 0; mi < 4; ++mi)
            #pragma unroll
            for (int ni = 0; ni < 4; ++ni)
                acc[mi][ni] = __builtin_amdgcn_mfma_f32_16x16x32_bf16(af[mi], bf[ni], acc[mi][ni], 0, 0, 0);
        __syncthreads();
    }

    #pragma unroll
    for (int mi = 0; mi < 4; ++mi)
        #pragma unroll
        for (int ni = 0; ni < 4; ++ni) {
            int col = n0 + wc * 64 + ni * 16 + c;
            float bv = bias[col];
            #pragma unroll
            for (int r = 0; r < 4; ++r) {
                int row = m0 + wr * 64 + mi * 16 + g * 4 + r;
                out[(size_t)row * EMB + col] = acc[mi][ni][r] + bv;
            }
        }
}

// ---------------- launch ----------------

extern "C" void kernel_launch(void* const* d_in, const int* in_sizes, int n_in,
                              void* d_out, int out_size, void* d_ws, size_t ws_size,
                              hipStream_t stream)
{
    const float* x      = (const float*)d_in[0];
    const float* W_attn = (const float*)d_in[1];
    const float* W_proj = (const float*)d_in[2];
    const float* b_proj = (const float*)d_in[3];
    float* out = (float*)d_out;

    char* ws = (char*)d_ws;
    hbf* xb    = (hbf*)ws; ws += (size_t)MTOT * KD * 2;
    hbf* wab_t = (hbf*)ws; ws += (size_t)N1 * KD * 2;
    hbf* wpb_t = (hbf*)ws; ws += (size_t)EMB * EMB * 2;
    hbf* qh    = (hbf*)ws; ws += (size_t)MTOT * EMB * 2;
    hbf* kh    = (hbf*)ws; ws += (size_t)MTOT * EMB * 2;
    hbf* vt    = (hbf*)ws; ws += (size_t)MTOT * EMB * 2;
    hbf* yb    = (hbf*)ws; ws += (size_t)MTOT * EMB * 2;

    f32_to_bf16<<<(MTOT * KD + 255) / 256, 256, 0, stream>>>(x, xb, MTOT * KD);
    f32_to_bf16_T<<<(KD * N1 + 255) / 256, 256, 0, stream>>>(W_attn, wab_t, KD, N1);
    f32_to_bf16_T<<<(KD * EMB + 255) / 256, 256, 0, stream>>>(W_proj, wpb_t, KD, EMB);

    gemm_qkv<<<(MTOT / BM) * (N1 / BN), 256, 0, stream>>>(xb, wab_t, qh, kh, vt);
    attn<<<BB * NH * 8, 256, 0, stream>>>(qh, kh, vt, yb);
    gemm_out<<<(MTOT / BM) * (EMB / BN), 256, 0, stream>>>(yb, wpb_t, b_proj, out);
}

// Round 7
// 285.884 us; speedup vs baseline: 4.4687x; 1.0144x over previous
//
#include <hip/hip_runtime.h>
#include <hip/hip_bf16.h>

#define NH 16
#define HD 64
#define EMB 1024
#define BB 4
#define TT 2048
#define MTOT (BB*TT)        // 8192 rows
#define N1 (3*NH*HD)        // 3072
#define KD EMB              // 1024

#define BM 128
#define BN 128
#define BK 32

// q scale: (1/sqrt(HD)) * log2(e) — softmax computed in exp2 domain
#define QSCALE 0.18033688011112042f

typedef __bf16 bf16x8 __attribute__((ext_vector_type(8)));
typedef __bf16 bf16x4 __attribute__((ext_vector_type(4)));
typedef float  f32x4  __attribute__((ext_vector_type(4)));
typedef __hip_bfloat16 hbf;

__device__ __forceinline__ void async_copy16(const hbf* g, hbf* l) {
    __builtin_amdgcn_global_load_lds(
        (const __attribute__((address_space(1))) void*)g,
        (__attribute__((address_space(3))) void*)l, 16, 0, 0);
}

__device__ __forceinline__ bf16x4 pack4(float x0, float x1, float x2, float x3) {
    union { bf16x4 v; hbf a[4]; } u;
    u.a[0] = __float2bfloat16(x0);
    u.a[1] = __float2bfloat16(x1);
    u.a[2] = __float2bfloat16(x2);
    u.a[3] = __float2bfloat16(x3);
    return u.v;
}

// ---------------- conversion kernels ----------------

__global__ __launch_bounds__(256) void f32_to_bf16_v4(const float* __restrict__ in,
                                                      hbf* __restrict__ out, int n4) {
    int i = blockIdx.x * blockDim.x + threadIdx.x;
    if (i < n4) {
        float4 v = ((const float4*)in)[i];
        *(bf16x4*)(out + 4 * (size_t)i) = pack4(v.x, v.y, v.z, v.w);
    }
}

// LDS-tiled transposing convert: out[c*R + r] = bf16(in[r*C + c]); R,C % 64 == 0
__global__ __launch_bounds__(256) void f32_to_bf16_T(const float* __restrict__ in,
                                                     hbf* __restrict__ out, int R, int C) {
    __shared__ float T[64][65];
    int bc = blockIdx.x % (C / 64), br = blockIdx.x / (C / 64);
    int r0 = br * 64, c0 = bc * 64;
    int tr = threadIdx.x >> 6, tc = threadIdx.x & 63;
    #pragma unroll
    for (int i = 0; i < 16; ++i)
        T[4 * i + tr][tc] = in[(size_t)(r0 + 4 * i + tr) * C + c0 + tc];
    __syncthreads();
    #pragma unroll
    for (int i = 0; i < 16; ++i)
        out[(size_t)(c0 + 4 * i + tr) * R + r0 + tc] = __float2bfloat16(T[tc][4 * i + tr]);
}

// ---------------- tiled GEMM core (m97 structure) ----------------

#define GEMM_STAGE(Sdst, Gsrc, ld)                                            \
    {                                                                         \
        _Pragma("unroll")                                                     \
        for (int q = 0; q < 2; ++q) {                                         \
            int e = q * 2048 + tid * 8;                                       \
            int row = e >> 5, col = e & 31;                                   \
            async_copy16(Gsrc + (size_t)row * (ld) + col,                     \
                         Sdst + q * 2048 + (tid & ~63) * 8);                  \
        }                                                                     \
    }

__global__ __launch_bounds__(256) void gemm_qkv(
    const hbf* __restrict__ A, const hbf* __restrict__ Bt,
    hbf* __restrict__ qh, hbf* __restrict__ kh, hbf* __restrict__ vt)
{
    __shared__ __align__(16) hbf As[BM * BK];
    __shared__ __align__(16) hbf Bs[BN * BK];
    int tid = threadIdx.x;
    int wv = tid >> 6, lane = tid & 63;
    int g = lane >> 4, c = lane & 15;
    int wr = wv >> 1, wc = wv & 1;
    int bn = blockIdx.x % (N1 / BN);
    int bm = blockIdx.x / (N1 / BN);
    int m0 = bm * BM, n0 = bn * BN;

    f32x4 acc[4][4];
    #pragma unroll
    for (int i = 0; i < 4; ++i)
        #pragma unroll
        for (int j = 0; j < 4; ++j) acc[i][j] = (f32x4){0.f, 0.f, 0.f, 0.f};

    for (int k0 = 0; k0 < KD; k0 += BK) {
        const hbf* Ag = A  + (size_t)m0 * KD + k0;
        const hbf* Bg = Bt + (size_t)n0 * KD + k0;
        GEMM_STAGE(As, Ag, KD);
        GEMM_STAGE(Bs, Bg, KD);
        __syncthreads();
        bf16x8 af[4], bf[4];
        #pragma unroll
        for (int mi = 0; mi < 4; ++mi)
            af[mi] = *(const bf16x8*)(As + (wr * 64 + mi * 16 + c) * BK + g * 8);
        #pragma unroll
        for (int ni = 0; ni < 4; ++ni)
            bf[ni] = *(const bf16x8*)(Bs + (wc * 64 + ni * 16 + c) * BK + g * 8);
        #pragma unroll
        for (int mi = 0; mi < 4; ++mi)
            #pragma unroll
            for (int ni = 0; ni < 4; ++ni)
                acc[mi][ni] = __builtin_amdgcn_mfma_f32_16x16x32_bf16(af[mi], bf[ni], acc[mi][ni], 0, 0, 0);
        __syncthreads();
    }

    int colbase = n0 + wc * 64;
    int which = colbase / (NH * HD);
    int h = (colbase % (NH * HD)) / HD;
    int b = m0 / TT;
    float scale = (which == 0) ? QSCALE : 1.0f;
    if (which < 2) {
        hbf* dst = (which == 0) ? qh : kh;
        dst += ((size_t)b * NH + h) * TT * HD;
        #pragma unroll
        for (int mi = 0; mi < 4; ++mi)
            #pragma unroll
            for (int ni = 0; ni < 4; ++ni) {
                int d = ni * 16 + c;
                #pragma unroll
                for (int r = 0; r < 4; ++r) {
                    int t = (m0 + wr * 64 + mi * 16 + g * 4 + r) % TT;
                    dst[(size_t)t * HD + d] = __float2bfloat16(acc[mi][ni][r] * scale);
                }
            }
    } else {
        hbf* dst = vt + ((size_t)b * NH + h) * TT * HD;   // [HD][TT] per head
        #pragma unroll
        for (int mi = 0; mi < 4; ++mi)
            #pragma unroll
            for (int ni = 0; ni < 4; ++ni) {
                int d = ni * 16 + c;
                #pragma unroll
                for (int r = 0; r < 4; ++r) {
                    int t = (m0 + wr * 64 + mi * 16 + g * 4 + r) % TT;
                    dst[(size_t)d * TT + t] = __float2bfloat16(acc[mi][ni][r]);
                }
            }
    }
}

// ---------------- flash attention v4: 8 waves x 16q, 128-key LDS stages ----------------
// Block = 512 thr = 8 waves, 128-q supertile (wave wv owns q rows qb+16wv..+15).
// Stage K[128x64] + V^T[64x128] per step (global_load_lds, XOR-swizzled source).
// S^T = K·Q^T (softmax in-lane, exp2 domain), O^T = V^T·P^T via per-wave LDS P.
// Causal balance: block runs supertile pair (pi, 15-pi) → uniform 17 stages.

__global__ __launch_bounds__(512, 4) void attn(
    const hbf* __restrict__ qh, const hbf* __restrict__ kh, const hbf* __restrict__ vt,
    hbf* __restrict__ y)
{
    __shared__ __align__(16) hbf Ks[128 * 64];     // 16 KB [key][dim-swz]
    __shared__ __align__(16) hbf Vs[64 * 128];     // 16 KB [dim][key-swz]
    __shared__ __align__(16) hbf Ps[8][16 * 64];   // 16 KB per-wave P^T

    int tid = threadIdx.x;
    int wv = tid >> 6, lane = tid & 63;
    int g = lane >> 4, c = lane & 15;
    int c7 = c & 7;

    int bh = blockIdx.x >> 3;
    int pi = blockIdx.x & 7;
    int b = bh >> 4, h = bh & 15;

    const hbf* Q = qh + (size_t)bh * TT * HD;
    const hbf* K = kh + (size_t)bh * TT * HD;
    const hbf* V = vt + (size_t)bh * TT * HD;   // [HD][TT]
    hbf* Pq = &Ps[wv][0];

    #pragma unroll
    for (int pass = 0; pass < 2; ++pass) {
        int sst = pass ? (15 - pi) : pi;
        int qb = sst * 128;
        int q0 = qb + wv * 16;
        int kend = q0 + 16;
        int kmax = qb + 128;

        bf16x8 aq0 = *(const bf16x8*)(Q + (size_t)(q0 + c) * HD + g * 8);
        bf16x8 aq1 = *(const bf16x8*)(Q + (size_t)(q0 + c) * HD + 32 + g * 8);

        float m = -1e30f, l = 0.f;
        f32x4 o[4];
        #pragma unroll
        for (int d = 0; d < 4; ++d) o[d] = (f32x4){0.f, 0.f, 0.f, 0.f};

        for (int k0 = 0; k0 < kmax; k0 += 128) {
            __syncthreads();   // prior stage's LDS reads complete
            // stage K tile 128x64: LDS[key][sblk] = K[k0+key][(sblk^(key&7))*8..]
            #pragma unroll
            for (int it = 0; it < 2; ++it) {
                int e = it * 4096 + tid * 8;
                int key = e >> 6, sblk = (e >> 3) & 7;
                int dblk = sblk ^ (key & 7);
                async_copy16(K + (size_t)(k0 + key) * HD + dblk * 8,
                             Ks + it * 4096 + (tid & ~63) * 8);
            }
            // stage V tile 64x128: LDS[dim][kb] = V[dim][k0 + (kb^(dim&7))*8..]
            #pragma unroll
            for (int it = 0; it < 2; ++it) {
                int e = it * 4096 + tid * 8;
                int dim = e >> 7, kb = (e >> 3) & 15;
                int skb = kb ^ (dim & 7);
                async_copy16(V + (size_t)dim * TT + k0 + skb * 8,
                             Vs + it * 4096 + (tid & ~63) * 8);
            }
            __syncthreads();   // staged

            #pragma unroll
            for (int ch = 0; ch < 2; ++ch) {
                int c64 = k0 + ch * 64;
                if (c64 < kend) {                         // wave-uniform
                    // ---- S^T = K·Q^T, 4 subtiles of 16 keys ----
                    f32x4 s[4];
                    #pragma unroll
                    for (int t = 0; t < 4; ++t) {
                        int kt = c64 + 16 * t;
                        if (kt < kend) {                  // wave-uniform
                            int rb = (ch * 64 + 16 * t + c) * 64;
                            bf16x8 kf0 = *(const bf16x8*)(Ks + rb + ((g ^ c7) << 3));
                            bf16x8 kf1 = *(const bf16x8*)(Ks + rb + (((4 + g) ^ c7) << 3));
                            f32x4 a = (f32x4){0.f, 0.f, 0.f, 0.f};
                            a = __builtin_amdgcn_mfma_f32_16x16x32_bf16(kf0, aq0, a, 0, 0, 0);
                            a = __builtin_amdgcn_mfma_f32_16x16x32_bf16(kf1, aq1, a, 0, 0, 0);
                            if (kt == q0) {               // diagonal: key<=q ⇔ g*4+r<=c
                                #pragma unroll
                                for (int r = 0; r < 4; ++r)
                                    a[r] = (g * 4 + r <= c) ? a[r] : -1e30f;
                            }
                            s[t] = a;
                        } else
                            s[t] = (f32x4){-1e30f, -1e30f, -1e30f, -1e30f};
                    }
                    // ---- online softmax (exp2 domain) ----
                    f32x4 vmax = s[0];
                    #pragma unroll
                    for (int t = 1; t < 4; ++t)
                        #pragma unroll
                        for (int r = 0; r < 4; ++r) vmax[r] = fmaxf(vmax[r], s[t][r]);
                    float mx = fmaxf(fmaxf(vmax[0], vmax[1]), fmaxf(vmax[2], vmax[3]));
                    mx = fmaxf(mx, __shfl_xor(mx, 16));
                    mx = fmaxf(mx, __shfl_xor(mx, 32));
                    float mn = fmaxf(m, mx);
                    float al = exp2f(m - mn);
                    m = mn;
                    f32x4 vsum = (f32x4){0.f, 0.f, 0.f, 0.f};
                    #pragma unroll
                    for (int t = 0; t < 4; ++t) {
                        f32x4 e;
                        #pragma unroll
                        for (int r = 0; r < 4; ++r) e[r] = exp2f(s[t][r] - mn);
                        vsum += e;
                        *(bf16x4*)(Pq + c * 64 + (((2 * t + (g >> 1)) ^ c7) << 3) + ((g & 1) << 2)) =
                            pack4(e[0], e[1], e[2], e[3]);
                    }
                    float sum = vsum[0] + vsum[1] + vsum[2] + vsum[3];
                    sum += __shfl_xor(sum, 16);
                    sum += __shfl_xor(sum, 32);
                    l = l * al + sum;
                    #pragma unroll
                    for (int d = 0; d < 4; ++d)
                        #pragma unroll
                        for (int r = 0; r < 4; ++r) o[d][r] *= al;
                    // ---- O^T += V^T·P^T ----
                    #pragma unroll
                    for (int sc = 0; sc < 2; ++sc) {
                        if (c64 + 32 * sc < kend) {       // wave-uniform
                            bf16x8 pf = *(const bf16x8*)(Pq + c * 64 + (((4 * sc + g) ^ c7) << 3));
                            #pragma unroll
                            for (int d = 0; d < 4; ++d) {
                                int dim = d * 16 + c;
                                bf16x8 vf = *(const bf16x8*)(Vs + dim * 128 +
                                              (((ch * 8 + 4 * sc + g) ^ c7) << 3));
                                o[d] = __builtin_amdgcn_mfma_f32_16x16x32_bf16(vf, pf, o[d], 0, 0, 0);
                            }
                        }
                    }
                }
            }
        }

        float inv = 1.0f / l;
        #pragma unroll
        for (int d = 0; d < 4; ++d) {
            *(bf16x4*)(y + (size_t)(b * TT + q0 + c) * EMB + h * HD + d * 16 + g * 4) =
                pack4(o[d][0] * inv, o[d][1] * inv, o[d][2] * inv, o[d][3] * inv);
        }
    }
}

// ---------------- GEMM 2: out = y @ W_proj + b_proj ----------------

__global__ __launch_bounds__(256) void gemm_out(
    const hbf* __restrict__ A, const hbf* __restrict__ Bt,
    const float* __restrict__ bias, float* __restrict__ out)
{
    __shared__ __align__(16) hbf As[BM * BK];
    __shared__ __align__(16) hbf Bs[BN * BK];
    int tid = threadIdx.x;
    int wv = tid >> 6, lane = tid & 63;
    int g = lane >> 4, c = lane & 15;
    int wr = wv >> 1, wc = wv & 1;
    int bn = blockIdx.x % (EMB / BN);
    int bm = blockIdx.x / (EMB / BN);
    int m0 = bm * BM, n0 = bn * BN;

    f32x4 acc[4][4];
    #pragma unroll
    for (int i = 0; i < 4; ++i)
        #pragma unroll
        for (int j = 0; j < 4; ++j) acc[i][j] = (f32x4){0.f, 0.f, 0.f, 0.f};

    for (int k0 = 0; k0 < EMB; k0 += BK) {
        const hbf* Ag = A  + (size_t)m0 * EMB + k0;
        const hbf* Bg = Bt + (size_t)n0 * EMB + k0;
        GEMM_STAGE(As, Ag, EMB);
        GEMM_STAGE(Bs, Bg, EMB);
        __syncthreads();
        bf16x8 af[4], bf[4];
        #pragma unroll
        for (int mi = 0; mi < 4; ++mi)
            af[mi] = *(const bf16x8*)(As + (wr * 64 + mi * 16 + c) * BK + g * 8);
        #pragma unroll
        for (int ni = 0; ni < 4; ++ni)
            bf[ni] = *(const bf16x8*)(Bs + (wc * 64 + ni * 16 + c) * BK + g * 8);
        #pragma unroll
        for (int mi = 0; mi < 4; ++mi)
            #pragma unroll
            for (int ni = 0; ni < 4; ++ni)
                acc[mi][ni] = __builtin_amdgcn_mfma_f32_16x16x32_bf16(af[mi], bf[ni], acc[mi][ni], 0, 0, 0);
        __syncthreads();
    }

    #pragma unroll
    for (int mi = 0; mi < 4; ++mi)
        #pragma unroll
        for (int ni = 0; ni < 4; ++ni) {
            int col = n0 + wc * 64 + ni * 16 + c;
            float bv = bias[col];
            #pragma unroll
            for (int r = 0; r < 4; ++r) {
                int row = m0 + wr * 64 + mi * 16 + g * 4 + r;
                out[(size_t)row * EMB + col] = acc[mi][ni][r] + bv;
            }
        }
}

// ---------------- launch ----------------

extern "C" void kernel_launch(void* const* d_in, const int* in_sizes, int n_in,
                              void* d_out, int out_size, void* d_ws, size_t ws_size,
                              hipStream_t stream)
{
    const float* x      = (const float*)d_in[0];
    const float* W_attn = (const float*)d_in[1];
    const float* W_proj = (const float*)d_in[2];
    const float* b_proj = (const float*)d_in[3];
    float* out = (float*)d_out;

    char* ws = (char*)d_ws;
    hbf* xb    = (hbf*)ws; ws += (size_t)MTOT * KD * 2;
    hbf* wab_t = (hbf*)ws; ws += (size_t)N1 * KD * 2;
    hbf* wpb_t = (hbf*)ws; ws += (size_t)EMB * EMB * 2;
    hbf* qh    = (hbf*)ws; ws += (size_t)MTOT * EMB * 2;
    hbf* kh    = (hbf*)ws; ws += (size_t)MTOT * EMB * 2;
    hbf* vt    = (hbf*)ws; ws += (size_t)MTOT * EMB * 2;
    hbf* yb    = (hbf*)ws; ws += (size_t)MTOT * EMB * 2;

    f32_to_bf16_v4<<<(MTOT * KD / 4 + 255) / 256, 256, 0, stream>>>(x, xb, MTOT * KD / 4);
    f32_to_bf16_T<<<(KD / 64) * (N1 / 64), 256, 0, stream>>>(W_attn, wab_t, KD, N1);
    f32_to_bf16_T<<<(KD / 64) * (EMB / 64), 256, 0, stream>>>(W_proj, wpb_t, KD, EMB);

    gemm_qkv<<<(MTOT / BM) * (N1 / BN), 256, 0, stream>>>(xb, wab_t, qh, kh, vt);
    attn<<<BB * NH * 8, 512, 0, stream>>>(qh, kh, vt, yb);
    gemm_out<<<(MTOT / BM) * (EMB / BN), 256, 0, stream>>>(yb, wpb_t, b_proj, out);
}